// Round 14
// baseline (237.267 us; speedup 1.0000x reference)
//
#include <hip/hip_runtime.h>

typedef __attribute__((ext_vector_type(8))) short short8;
typedef __attribute__((ext_vector_type(16))) float f32x16;

// ws layout:
//   Ft2  [z=512][yy=66][xx=66][8] bf16 halo-padded features, z = c*8 + b   (35.68 MB)
//   wt2  [slab=72][e=8][n=128][8] bf16 B slabs, e = i&7 (chunk-major)      (1.18 MB)
#define FT2_SHORTS (512u * 4356u * 8u)
#define PLANE16    4356

typedef __attribute__((address_space(3))) unsigned int lds_u32_t;
typedef __attribute__((address_space(1))) const unsigned int g_u32_t;

__device__ __forceinline__ unsigned short f2bf(float x) {
    union { float f; unsigned u; } v; v.f = x;
    unsigned r = v.u + 0x7FFFu + ((v.u >> 16) & 1u);   // RNE bf16
    return (unsigned short)(r >> 16);
}

__device__ __forceinline__ void feat8(float p, unsigned short* uf) {
    float e   = __expf(-p);
    float sig = 1.f / (1.f + e);
    uf[0] = f2bf(p * sig);
    float u  = p * 1.5f + 4.5f;
    float fj = floorf(u);
    int   j0 = (int)fj;
    float t  = u - fj;
    bool  inr = (u >= 0.f) && (u < 9.f);
    float t2 = t * t, t3 = t2 * t;
    const float c16 = 1.f / 6.f;
    float r0 = t3 * c16;
    float r1 = (-3.f * t3 + 3.f * t2 + 3.f * t + 1.f) * c16;
    float r2 = (3.f * t3 - 6.f * t2 + 4.f) * c16;
    float s1 = 1.f - t;
    float r3 = s1 * s1 * s1 * c16;
#pragma unroll
    for (int g = 0; g < 6; ++g) {
        int r = j0 - g;
        float v = (r == 0) ? r0 : ((r == 1) ? r1 : ((r == 2) ? r2 : ((r == 3) ? r3 : 0.f)));
        uf[1 + g] = f2bf(inr ? v : 0.f);
    }
    uf[7] = 0;
}

// ---- Prep v2 (R11 verbatim): grid 2048 x 256, no LDS/sync/dep-chains ----
__global__ __launch_bounds__(256)
void prep_all(const float* __restrict__ x,
              const float* __restrict__ bw, const float* __restrict__ sw,
              unsigned short* __restrict__ ft, unsigned short* __restrict__ wt) {
    const int blk  = blockIdx.x;         // 0..2047
    const int tid  = threadIdx.x;
    const int line = blk >> 2;           // 0..511 (also halo plane z)
    const int q    = blk & 3;            // channel quarter

    // (1) B prep into slab-chunk-major layout: wt[slab][i&7][n][8]
    if (tid < 36) {
        int idx = blk * 36 + tid;        // 2048*36 = 73728 = 576*128
        int o = idx / 576;
        int i = idx - o * 576;
        int slab = i >> 3, e = i & 7;
        union { unsigned short u[8]; uint4 v; } pk;
        pk.u[0] = f2bf(bw[o * 576 + i]);
        const float* s = sw + (size_t)(o * 576 + i) * 6;
#pragma unroll
        for (int f = 0; f < 6; ++f) pk.u[1 + f] = f2bf(s[f]);
        pk.u[7] = 0;
        *(uint4*)(wt + ((size_t)slab * 8192 + e * 1024 + o * 8)) = pk.v;
    }

    // (2) halo plane z = line: 260 border cells split 65 per quarter
    if (tid < 65) {
        int t = q * 65 + tid;            // 0..259
        short8 pad = { 0, 0, (short)0x3CAB, (short)0x3EF5,
                       (short)0x3EF5, (short)0x3CAB, 0, 0 };
        int yy, xx;
        if (t < 66)       { yy = 0;       xx = t; }
        else if (t < 132) { yy = 65;      xx = t - 66; }
        else if (t < 196) { yy = t - 131; xx = 0; }
        else              { yy = t - 195; xx = 65; }
        ((short8*)ft)[line * PLANE16 + yy * 66 + xx] = pad;
    }

    // (3) features: thread (xx, cw) handles channels c0..c0+3 of pixel (line, xx)
    const int xx = tid & 63;
    const int cw = tid >> 6;             // 0..3
    const int b  = line >> 6, y = line & 63;
    const int c0 = q * 16 + cw * 4;
    const float4 v = *(const float4*)(x + (size_t)line * 4096 + xx * 64 + c0);

    union { unsigned short u[8]; uint4 w; } p0, p1, p2, p3;
    feat8(v.x, p0.u); feat8(v.y, p1.u); feat8(v.z, p2.u); feat8(v.w, p3.u);

    const size_t cell = (size_t)(y + 1) * 66 + (xx + 1);
    *(uint4*)(ft + ((((size_t)((c0 + 0) * 8 + b) * PLANE16) + cell) << 3)) = p0.w;
    *(uint4*)(ft + ((((size_t)((c0 + 1) * 8 + b) * PLANE16) + cell) << 3)) = p1.w;
    *(uint4*)(ft + ((((size_t)((c0 + 2) * 8 + b) * PLANE16) + cell) << 3)) = p2.w;
    *(uint4*)(ft + ((((size_t)((c0 + 3) * 8 + b) * PLANE16) + cell) << 3)) = p3.w;
}

// ---- Main GEMM: tile 128m(2 lines) x 128n, K-split 2, grid 512, block 512 ----
// DMA-rate model (13 rounds): phased designs saturate ~15 TB/s chip of
// global->LDS service; R6 staged 900 MB (B re-read 512x) = 56.6 us floor.
// This round: 128-px tiles halve B re-reads -> 600 MB staged (~40 us floor),
// keeping grid 512 = 2 blocks/CU (decoupling that achieves the top rate) via
// K-split 2 (atomics proven free, R0/R1). Full-slab 32 KB phases (R7's 16 KB
// phases fell off the rate curve), DOUBLE-buffered (2x32 KB = 64 KB -> 2
// blocks/CU), counted vmcnt(4) keeps one phase in flight (not R0's full drain).
// Waves (kq 0..1, mh, nh): kq owns K16 steps {2kq, 2kq+1} of the slab; wave
// tile 64px(line mh) x 64n, 4 accs, 8 ds_read + 8 MFMA per phase.
// Epilogue: one-round kq-reduction in LDS, then f32 atomicAdd (+ bias, kk=0).
#define BUF_SHORTS 16384

#define STAGE(sl, q_)                                                                 \
    {                                                                                 \
        unsigned short* bufq = Bufs + (q_) * BUF_SHORTS;                              \
        const unsigned short* bsrc = wt + (size_t)(sl) * 8192;                        \
        _Pragma("unroll")                                                             \
        for (int t = 0; t < 4; ++t) {                                                 \
            int u = wave * 4 + t;            /* 0..31: u<16 = B, u>=16 = A */         \
            if (u < 16) {                                                             \
                int boff = u * 512 + lane * 8;                                        \
                __builtin_amdgcn_global_load_lds((g_u32_t*)(bsrc + boff),             \
                                                 (lds_u32_t*)(bufq + boff), 16, 0, 0);\
            } else {                                                                  \
                int ua  = u - 16;            /* chunk*2 + line, 0..15 */              \
                int ia  = (sl) * 8 + (ua >> 1);                                       \
                int ln  = ua & 1;                                                     \
                int c_  = (ia * 7282) >> 16;                                          \
                int i9_ = ia - c_ * 9;                                                \
                int kh_ = (i9_ * 11) >> 5;                                            \
                int kw_ = i9_ - kh_ * 3;                                              \
                const unsigned short* asrc = ft +                                     \
                    (((size_t)(c_ * 8 + b) * PLANE16 + (y0 + ln + kh_) * 66 + kw_)    \
                     << 3) + lane * 8;                                                \
                unsigned short* adst = bufq + 8192 + ua * 512 + lane * 8;             \
                __builtin_amdgcn_global_load_lds((g_u32_t*)asrc, (lds_u32_t*)adst,    \
                                                 16, 0, 0);                           \
            }                                                                         \
        }                                                                             \
    }

#define COMPUTE(q_)                                                                   \
    {                                                                                 \
        const unsigned short* bufr = Bufs + (q_) * BUF_SHORTS;                        \
        short8 a0, a1, b0, b1;                                                        \
        a0 = *(const short8*)(bufr + ao0);                                            \
        a1 = *(const short8*)(bufr + ao0 + 256);                                      \
        b0 = *(const short8*)(bufr + bo0);                                            \
        b1 = *(const short8*)(bufr + bo0 + 256);                                      \
        acc00 = __builtin_amdgcn_mfma_f32_32x32x16_bf16(a0, b0, acc00, 0, 0, 0);      \
        acc01 = __builtin_amdgcn_mfma_f32_32x32x16_bf16(a0, b1, acc01, 0, 0, 0);      \
        acc10 = __builtin_amdgcn_mfma_f32_32x32x16_bf16(a1, b0, acc10, 0, 0, 0);      \
        acc11 = __builtin_amdgcn_mfma_f32_32x32x16_bf16(a1, b1, acc11, 0, 0, 0);      \
        a0 = *(const short8*)(bufr + ao1);                                            \
        a1 = *(const short8*)(bufr + ao1 + 256);                                      \
        b0 = *(const short8*)(bufr + bo1);                                            \
        b1 = *(const short8*)(bufr + bo1 + 256);                                      \
        acc00 = __builtin_amdgcn_mfma_f32_32x32x16_bf16(a0, b0, acc00, 0, 0, 0);      \
        acc01 = __builtin_amdgcn_mfma_f32_32x32x16_bf16(a0, b1, acc01, 0, 0, 0);      \
        acc10 = __builtin_amdgcn_mfma_f32_32x32x16_bf16(a1, b0, acc10, 0, 0, 0);      \
        acc11 = __builtin_amdgcn_mfma_f32_32x32x16_bf16(a1, b1, acc11, 0, 0, 0);      \
    }

#define PHASE(q_, n_, stagesl, dostage_)                                              \
    {                                                                                 \
        asm volatile("s_waitcnt vmcnt(" #n_ ")" ::: "memory");                        \
        __builtin_amdgcn_s_barrier();                                                 \
        asm volatile("" ::: "memory");                                                \
        __builtin_amdgcn_s_setprio(1);                                                \
        COMPUTE(q_)                                                                   \
        __builtin_amdgcn_s_setprio(0);                                                \
        asm volatile("" ::: "memory");                                                \
        __builtin_amdgcn_s_barrier();                                                 \
        asm volatile("" ::: "memory");                                                \
        if (dostage_) STAGE(stagesl, q_);                                             \
    }

// Epilogue reduce helpers: conflict-free float4 layout (lane-stride 16 B).
#define DUMPA(base_, A_)                                                              \
    {   float4* s4 = (float4*)(red + (base_));                                        \
        _Pragma("unroll")                                                             \
        for (int c = 0; c < 4; ++c)                                                   \
            s4[c * 64 + lane] = make_float4(A_[4*c], A_[4*c+1], A_[4*c+2], A_[4*c+3]); }
#define ADDA(base_, A_)                                                               \
    {   const float4* s4 = (const float4*)(red + (base_));                            \
        _Pragma("unroll")                                                             \
        for (int c = 0; c < 4; ++c) {                                                 \
            float4 rv = s4[c * 64 + lane];                                            \
            A_[4*c] += rv.x; A_[4*c+1] += rv.y; A_[4*c+2] += rv.z; A_[4*c+3] += rv.w; } }

__global__ __launch_bounds__(512, 4)
void convkan_gemm(const unsigned short* __restrict__ ft,
                  const unsigned short* __restrict__ wt,
                  const float* __restrict__ bias,
                  float* __restrict__ out) {
    extern __shared__ unsigned short Bufs[];     // 2 x 16384 shorts = 64 KB

    const int tid  = threadIdx.x;
    const int blk  = blockIdx.x;                 // 0..511
    const int kk   = blk >> 8;                   // K-half (slabs kk*36..+35)
    const int mbr  = blk & 255;
    const int mb   = ((mbr & 7) << 5) | (mbr >> 3);  // XCD swizzle: XCD owns image
    const int lane = tid & 63;
    const int wave = tid >> 6;                   // 0..7
    const int kq   = wave >> 2;                  // K16-step pair within slab (0..1)
    const int mh   = (wave >> 1) & 1;            // line within 2-line tile
    const int nh   = wave & 1;                   // n-half (64 ch)
    const int l32  = lane & 31;
    const int h    = lane >> 5;                  // k-half within MFMA K16

    const int b  = mb >> 5;                      // image 0..7
    const int y0 = (mb & 31) << 1;               // first of 2 lines
    const int kk36 = kk * 36;

    // per-phase LDS offsets (shorts): steps s = 2kq+st, e-slice iloc = 2s+h
    const int il0 = 4 * kq + h;                  // st=0
    const int il1 = 4 * kq + 2 + h;              // st=1
    const int ao0 = 8192 + (il0 * 2 + mh) * 512 + l32 * 8;
    const int ao1 = 8192 + (il1 * 2 + mh) * 512 + l32 * 8;
    const int bo0 = il0 * 1024 + nh * 512 + l32 * 8;
    const int bo1 = il1 * 1024 + nh * 512 + l32 * 8;

    f32x16 acc00, acc01, acc10, acc11;
#pragma unroll
    for (int e = 0; e < 16; ++e) { acc00[e] = 0.f; acc01[e] = 0.f; acc10[e] = 0.f; acc11[e] = 0.f; }

    // prologue: fill the 2-deep pipeline (slabs kk36+0, kk36+1)
    STAGE(kk36 + 0, 0);
    STAGE(kk36 + 1, 1);

    // phases 0..33: compute slab it, stage slab it+2 (2..35)
    for (int it2 = 0; it2 < 17; ++it2) {
        const int it = it2 * 2;
        PHASE(0, 4, kk36 + it + 2, true)
        PHASE(1, 4, kk36 + it + 3, true)
    }
    // phases 34, 35: drain
    PHASE(0, 4, 0, false)
    PHASE(1, 0, 0, false)

    // ---- kq-reduction (one LDS round), then atomic store ----
    __syncthreads();
    float* red = (float*)Bufs;
    const int grp = mh * 2 + nh;                 // 0..3 -> 16 KB region each

    if (kq == 1) {
        DUMPA(grp * 4096,        acc00); DUMPA(grp * 4096 + 1024, acc01);
        DUMPA(grp * 4096 + 2048, acc10); DUMPA(grp * 4096 + 3072, acc11);
    }
    __syncthreads();
    if (kq == 0) {
        ADDA(grp * 4096,        acc00); ADDA(grp * 4096 + 1024, acc01);
        ADDA(grp * 4096 + 2048, acc10); ADDA(grp * 4096 + 3072, acc11);

        const int ncol = nh * 64 + l32;
        const float bv0 = kk ? 0.f : bias[ncol];
        const float bv1 = kk ? 0.f : bias[ncol + 32];
        const int prow = mb * 128 + mh * 64;     // line mh of the 2-line tile
#pragma unroll
        for (int r = 0; r < 16; ++r) {
            int mrow = (r & 3) + ((r >> 2) << 3) + 4 * h;
            float* p = out + (size_t)(prow + mrow) * 128 + ncol;
            atomicAdd(p,      acc00[r] + bv0);
            atomicAdd(p + 32, acc01[r] + bv1);
            float* p2 = out + (size_t)(prow + 32 + mrow) * 128 + ncol;
            atomicAdd(p2,      acc10[r] + bv0);
            atomicAdd(p2 + 32, acc11[r] + bv1);
        }
    }
}

extern "C" void kernel_launch(void* const* d_in, const int* in_sizes, int n_in,
                              void* d_out, int out_size, void* d_ws, size_t ws_size,
                              hipStream_t stream) {
    (void)in_sizes; (void)n_in; (void)ws_size;
    const float* x        = (const float*)d_in[0];
    const float* base_w   = (const float*)d_in[1];
    const float* spline_w = (const float*)d_in[2];
    const float* bias     = (const float*)d_in[3];
    float* out = (float*)d_out;

    unsigned short* ft = (unsigned short*)d_ws;      // 35.68 MB halo features
    unsigned short* wt = ft + FT2_SHORTS;            // 1.18 MB tiled B (slab-major)

    hipMemsetAsync(out, 0, (size_t)out_size * sizeof(float), stream);
    hipLaunchKernelGGL(prep_all, dim3(2048), dim3(256), 0, stream,
                       x, base_w, spline_w, ft, wt);

    const int shmem = 2 * BUF_SHORTS * 2;            // 64 KB -> 2 blocks/CU
    (void)hipFuncSetAttribute((const void*)convkan_gemm,
                              hipFuncAttributeMaxDynamicSharedMemorySize, shmem);
    hipLaunchKernelGGL(convkan_gemm, dim3(512), dim3(512), shmem, stream,
                       ft, wt, bias, out);
}

// Round 15
// 129.917 us; speedup vs baseline: 1.8263x; 1.8263x over previous
//
#include <hip/hip_runtime.h>

typedef __attribute__((ext_vector_type(8))) short short8;
typedef __attribute__((ext_vector_type(16))) float f32x16;

// ws layout:
//   Ft2  [z=512][yy=66][xx=66][8] bf16 halo-padded features, z = c*8 + b   (35.68 MB)
//   wt2  [slab=72][e=8][n=128][8] bf16 B slabs, e = i&7 (chunk-major)      (1.18 MB)
#define FT2_SHORTS (512u * 4356u * 8u)
#define PLANE16    4356

typedef __attribute__((address_space(3))) unsigned int lds_u32_t;
typedef __attribute__((address_space(1))) const unsigned int g_u32_t;

__device__ __forceinline__ unsigned short f2bf(float x) {
    union { float f; unsigned u; } v; v.f = x;
    unsigned r = v.u + 0x7FFFu + ((v.u >> 16) & 1u);   // RNE bf16
    return (unsigned short)(r >> 16);
}

__device__ __forceinline__ void feat8(float p, unsigned short* uf) {
    float e   = __expf(-p);
    float sig = 1.f / (1.f + e);
    uf[0] = f2bf(p * sig);
    float u  = p * 1.5f + 4.5f;
    float fj = floorf(u);
    int   j0 = (int)fj;
    float t  = u - fj;
    bool  inr = (u >= 0.f) && (u < 9.f);
    float t2 = t * t, t3 = t2 * t;
    const float c16 = 1.f / 6.f;
    float r0 = t3 * c16;
    float r1 = (-3.f * t3 + 3.f * t2 + 3.f * t + 1.f) * c16;
    float r2 = (3.f * t3 - 6.f * t2 + 4.f) * c16;
    float s1 = 1.f - t;
    float r3 = s1 * s1 * s1 * c16;
#pragma unroll
    for (int g = 0; g < 6; ++g) {
        int r = j0 - g;
        float v = (r == 0) ? r0 : ((r == 1) ? r1 : ((r == 2) ? r2 : ((r == 3) ? r3 : 0.f)));
        uf[1 + g] = f2bf(inr ? v : 0.f);
    }
    uf[7] = 0;
}

// ---- Prep v2: throughput layout. Grid 2048 x 256 (8 blocks/CU), no LDS,
// no syncthreads, no dependent chains. Block = (line 0..511, q 0..3).
__global__ __launch_bounds__(256)
void prep_all(const float* __restrict__ x,
              const float* __restrict__ bw, const float* __restrict__ sw,
              unsigned short* __restrict__ ft, unsigned short* __restrict__ wt) {
    const int blk  = blockIdx.x;         // 0..2047
    const int tid  = threadIdx.x;
    const int line = blk >> 2;           // 0..511 (also halo plane z)
    const int q    = blk & 3;            // channel quarter

    // (1) B prep into slab-chunk-major layout: wt[slab][i&7][n][8]
    if (tid < 36) {
        int idx = blk * 36 + tid;        // 2048*36 = 73728 = 576*128
        int o = idx / 576;
        int i = idx - o * 576;
        int slab = i >> 3, e = i & 7;
        union { unsigned short u[8]; uint4 v; } pk;
        pk.u[0] = f2bf(bw[o * 576 + i]);
        const float* s = sw + (size_t)(o * 576 + i) * 6;
#pragma unroll
        for (int f = 0; f < 6; ++f) pk.u[1 + f] = f2bf(s[f]);
        pk.u[7] = 0;
        *(uint4*)(wt + ((size_t)slab * 8192 + e * 1024 + o * 8)) = pk.v;
    }

    // (2) halo plane z = line: 260 border cells split 65 per quarter
    if (tid < 65) {
        int t = q * 65 + tid;            // 0..259
        short8 pad = { 0, 0, (short)0x3CAB, (short)0x3EF5,
                       (short)0x3EF5, (short)0x3CAB, 0, 0 };
        int yy, xx;
        if (t < 66)       { yy = 0;       xx = t; }
        else if (t < 132) { yy = 65;      xx = t - 66; }
        else if (t < 196) { yy = t - 131; xx = 0; }
        else              { yy = t - 195; xx = 65; }
        ((short8*)ft)[line * PLANE16 + yy * 66 + xx] = pad;
    }

    // (3) features: thread (xx, cw) handles channels c0..c0+3 of pixel (line, xx)
    const int xx = tid & 63;
    const int cw = tid >> 6;             // 0..3
    const int b  = line >> 6, y = line & 63;
    const int c0 = q * 16 + cw * 4;
    const float4 v = *(const float4*)(x + (size_t)line * 4096 + xx * 64 + c0);

    union { unsigned short u[8]; uint4 w; } p0, p1, p2, p3;
    feat8(v.x, p0.u); feat8(v.y, p1.u); feat8(v.z, p2.u); feat8(v.w, p3.u);

    const size_t cell = (size_t)(y + 1) * 66 + (xx + 1);
    *(uint4*)(ft + ((((size_t)((c0 + 0) * 8 + b) * PLANE16) + cell) << 3)) = p0.w;
    *(uint4*)(ft + ((((size_t)((c0 + 1) * 8 + b) * PLANE16) + cell) << 3)) = p1.w;
    *(uint4*)(ft + ((((size_t)((c0 + 2) * 8 + b) * PLANE16) + cell) << 3)) = p2.w;
    *(uint4*)(ft + ((((size_t)((c0 + 3) * 8 + b) * PLANE16) + cell) << 3)) = p3.w;
}

// ---- Main GEMM (best measured: 56.7-59 us, clean counters) ----
// tile 64m(1 line) x 128n, FULL K (72 slabs), grid 512, block 512 (8 waves),
// 2 blocks/CU (72 KB LDS each = two independent barrier domains), XCD swizzle.
// TRIPLE-buffered 24 KB phases (B 16 KB + A 8 KB): a stage has TWO full phases
// to land before its vmcnt gate (R14 lesson: double-buffer = one tiny phase of
// cover -> full latency exposed, 3x slower). Steady vmcnt(6); 3 loads/thread.
#define BUF_SHORTS 12288

#define STAGE(sl, q_)                                                                 \
    {                                                                                 \
        unsigned short* bufq = Bufs + (q_) * BUF_SHORTS;                              \
        const unsigned short* bsrc = wt + (size_t)(sl) * 8192;                        \
        _Pragma("unroll")                                                             \
        for (int t = 0; t < 3; ++t) {                                                 \
            int u = wave * 3 + t;            /* 0..23: u<16 = B, u>=16 = A */         \
            if (u < 16) {                                                             \
                int boff = u * 512 + lane * 8;                                        \
                __builtin_amdgcn_global_load_lds((g_u32_t*)(bsrc + boff),             \
                                                 (lds_u32_t*)(bufq + boff), 16, 0, 0);\
            } else {                                                                  \
                int idx = u - 16;            /* chunk 0..7 */                         \
                int ia  = (sl) * 8 + idx;                                             \
                int c_  = (ia * 7282) >> 16;                                          \
                int i9_ = ia - c_ * 9;                                                \
                int kh_ = (i9_ * 11) >> 5;                                            \
                int kw_ = i9_ - kh_ * 3;                                              \
                const unsigned short* asrc = ft +                                     \
                    (((size_t)(c_ * 8 + b) * PLANE16 + (y + kh_) * 66 + kw_) << 3)    \
                    + lane * 8;                                                       \
                unsigned short* adst = bufq + 8192 + idx * 512 + lane * 8;            \
                __builtin_amdgcn_global_load_lds((g_u32_t*)asrc, (lds_u32_t*)adst,    \
                                                 16, 0, 0);                           \
            }                                                                         \
        }                                                                             \
    }

#define COMPUTE(q_)                                                                   \
    {                                                                                 \
        const unsigned short* bufr = Bufs + (q_) * BUF_SHORTS;                        \
        const unsigned short* Ab = bufr + 8192 + iloc * 512;                          \
        const unsigned short* Bb = bufr + iloc * 1024 + nh * 512;                     \
        short8 a0 = *(const short8*)(Ab + l32 * 8);                                   \
        short8 a1 = *(const short8*)(Ab + (32 + l32) * 8);                            \
        short8 b0 = *(const short8*)(Bb + l32 * 8);                                   \
        short8 b1 = *(const short8*)(Bb + 256 + l32 * 8);                             \
        acc00 = __builtin_amdgcn_mfma_f32_32x32x16_bf16(a0, b0, acc00, 0, 0, 0);      \
        acc01 = __builtin_amdgcn_mfma_f32_32x32x16_bf16(a0, b1, acc01, 0, 0, 0);      \
        acc10 = __builtin_amdgcn_mfma_f32_32x32x16_bf16(a1, b0, acc10, 0, 0, 0);      \
        acc11 = __builtin_amdgcn_mfma_f32_32x32x16_bf16(a1, b1, acc11, 0, 0, 0);      \
    }

#define PHASE(q_, n_, stagesl, dostage_)                                              \
    {                                                                                 \
        asm volatile("s_waitcnt vmcnt(" #n_ ")" ::: "memory");                        \
        __builtin_amdgcn_s_barrier();                                                 \
        asm volatile("" ::: "memory");                                                \
        __builtin_amdgcn_s_setprio(1);                                                \
        COMPUTE(q_)                                                                   \
        __builtin_amdgcn_s_setprio(0);                                                \
        asm volatile("" ::: "memory");                                                \
        __builtin_amdgcn_s_barrier();                                                 \
        asm volatile("" ::: "memory");                                                \
        if (dostage_) STAGE(stagesl, q_);                                             \
    }

// Epilogue reduce helpers: conflict-free float4 layout (lane-stride 16 B).
#define DUMPA(base_, A_)                                                              \
    {   float4* s4 = (float4*)(red + (base_));                                        \
        _Pragma("unroll")                                                             \
        for (int c = 0; c < 4; ++c)                                                   \
            s4[c * 64 + lane] = make_float4(A_[4*c], A_[4*c+1], A_[4*c+2], A_[4*c+3]); }
#define ADDA(base_, A_)                                                               \
    {   const float4* s4 = (const float4*)(red + (base_));                            \
        _Pragma("unroll")                                                             \
        for (int c = 0; c < 4; ++c) {                                                 \
            float4 rv = s4[c * 64 + lane];                                            \
            A_[4*c] += rv.x; A_[4*c+1] += rv.y; A_[4*c+2] += rv.z; A_[4*c+3] += rv.w; } }

__global__ __launch_bounds__(512, 4)
void convkan_gemm(const unsigned short* __restrict__ ft,
                  const unsigned short* __restrict__ wt,
                  const float* __restrict__ bias,
                  float* __restrict__ out) {
    extern __shared__ unsigned short Bufs[];     // 3 x 12288 shorts = 72 KB

    const int tid  = threadIdx.x;
    const int blk  = blockIdx.x;                 // 0..511
    const int mb   = ((blk & 7) << 6) | (blk >> 3);  // XCD swizzle: XCD owns image
    const int lane = tid & 63;
    const int wave = tid >> 6;                   // 0..7
    const int kq   = wave >> 1;                  // K-quarter 0..3
    const int nh   = wave & 1;                   // n-half (64 ch)
    const int l32  = lane & 31;
    const int h    = lane >> 5;                  // k-half within MFMA K16
    const int iloc = (kq << 1) + h;              // e-chunk this half-wave consumes

    const int b = mb >> 6;                       // image 0..7
    const int y = mb & 63;                       // line 0..63

    f32x16 acc00, acc01, acc10, acc11;
#pragma unroll
    for (int e = 0; e < 16; ++e) { acc00[e] = 0.f; acc01[e] = 0.f; acc10[e] = 0.f; acc11[e] = 0.f; }

    // prologue: fill the 3-deep pipeline
    STAGE(0, 0);
    STAGE(1, 1);
    STAGE(2, 2);

    // steady state: phases 0..68 stage slabs 3..71
    for (int it3 = 0; it3 < 23; ++it3) {
        const int it = it3 * 3;
        PHASE(0, 6, it + 3, true)
        PHASE(1, 6, it + 4, true)
        PHASE(2, 6, it + 5, true)
    }
    // tail: phases 69, 70, 71 — drain pipeline
    PHASE(0, 6, 0, false)
    PHASE(1, 3, 0, false)
    PHASE(2, 0, 0, false)

    // ---- K-partial reduction across kq (3 rounds via LDS), then store ----
    __syncthreads();
    float* red = (float*)Bufs;

    if (kq >= 2) { DUMPA(((nh << 1) + (kq - 2)) * 2048,        acc00);
                   DUMPA(((nh << 1) + (kq - 2)) * 2048 + 1024, acc01); }
    __syncthreads();
    if (kq < 2)  { ADDA(((nh << 1) + kq) * 2048,        acc00);
                   ADDA(((nh << 1) + kq) * 2048 + 1024, acc01); }
    __syncthreads();
    if (kq >= 2) { DUMPA(((nh << 1) + (kq - 2)) * 2048,        acc10);
                   DUMPA(((nh << 1) + (kq - 2)) * 2048 + 1024, acc11); }
    __syncthreads();
    if (kq < 2)  { ADDA(((nh << 1) + kq) * 2048,        acc10);
                   ADDA(((nh << 1) + kq) * 2048 + 1024, acc11); }
    __syncthreads();
    if (kq == 1) { DUMPA(nh * 4096,        acc00); DUMPA(nh * 4096 + 1024, acc01);
                   DUMPA(nh * 4096 + 2048, acc10); DUMPA(nh * 4096 + 3072, acc11); }
    __syncthreads();
    if (kq == 0) {
        ADDA(nh * 4096,        acc00); ADDA(nh * 4096 + 1024, acc01);
        ADDA(nh * 4096 + 2048, acc10); ADDA(nh * 4096 + 3072, acc11);

        const int ncol = nh * 64 + l32;
        const float bv0 = bias[ncol];
        const float bv1 = bias[ncol + 32];
        const int prow = mb * 64;                // output pixel-row base
#pragma unroll
        for (int r = 0; r < 16; ++r) {
            int mrow = (r & 3) + ((r >> 2) << 3) + 4 * h;
            float* p = out + (size_t)(prow + mrow) * 128 + ncol;
            p[0]  = acc00[r] + bv0;
            p[32] = acc01[r] + bv1;
            float* p2 = out + (size_t)(prow + 32 + mrow) * 128 + ncol;
            p2[0]  = acc10[r] + bv0;
            p2[32] = acc11[r] + bv1;
        }
    }
}

extern "C" void kernel_launch(void* const* d_in, const int* in_sizes, int n_in,
                              void* d_out, int out_size, void* d_ws, size_t ws_size,
                              hipStream_t stream) {
    (void)in_sizes; (void)n_in; (void)ws_size; (void)out_size;
    const float* x        = (const float*)d_in[0];
    const float* base_w   = (const float*)d_in[1];
    const float* spline_w = (const float*)d_in[2];
    const float* bias     = (const float*)d_in[3];
    float* out = (float*)d_out;

    unsigned short* ft = (unsigned short*)d_ws;      // 35.68 MB halo features
    unsigned short* wt = ft + FT2_SHORTS;            // 1.18 MB tiled B (slab-major)

    hipLaunchKernelGGL(prep_all, dim3(2048), dim3(256), 0, stream,
                       x, base_w, spline_w, ft, wt);

    const int shmem = 3 * BUF_SHORTS * 2;            // 72 KB -> 2 blocks/CU
    (void)hipFuncSetAttribute((const void*)convkan_gemm,
                              hipFuncAttributeMaxDynamicSharedMemorySize, shmem);
    hipLaunchKernelGGL(convkan_gemm, dim3(512), dim3(512), shmem, stream,
                       ft, wt, bias, out);
}